// Round 12
// baseline (178.814 us; speedup 1.0000x reference)
//
#include <hip/hip_runtime.h>

// 3x3 median filter, zero-padded, (32,3,512,512) fp32.
// Round 12: software-pipelined LDS staging (2-phase, double-buffered).
// Per block: 6 tiles of 8 output rows. Each tile stages 10 rows x 512 cols
// (20 KB) into LDS via __builtin_amdgcn_global_load_lds (16B, fire-and-forget).
// Loop: stage(tile t+1 -> buf^1) BEFORE compute(tile t from buf) so the next
// tile's reads stay in flight under compute + stores; one barrier per tile.
// 2x20 KB LDS -> 4 blocks/CU resident -> ~80 KB reads in flight per CU.
// Median-of-9 = med3(max3(row mins), med3(row meds), min3(row maxes)) over
// sorted horizontal triples (exact; v_min3/v_med3/v_max3).

#define H 512
#define W 512
#define TR 8                          // output rows per tile
#define TILE_ROWS (TR + 2)            // 10 staged rows
#define STRIPS (H / TR)               // 64
#define TPB 6                         // tiles per block
#define BUF_ELEMS (TILE_ROWS * W)     // 5120 floats = 20480 B
#define STAGE_ROUNDS (BUF_ELEMS / (256 * 4))   // 5

__device__ __forceinline__ float f_min3(float a, float b, float c) { return fminf(fminf(a, b), c); }
__device__ __forceinline__ float f_max3(float a, float b, float c) { return fmaxf(fmaxf(a, b), c); }
__device__ __forceinline__ float f_med3(float a, float b, float c) { return __builtin_amdgcn_fmed3f(a, b, c); }

__global__ __launch_bounds__(256) void median3x3_kernel(const float* __restrict__ in,
                                                        float* __restrict__ out) {
    __shared__ float buf[2][BUF_ELEMS];   // 40960 B total

    int bid = blockIdx.x;
    int tid = threadIdx.x;

    // ---- stage one tile (10 rows) into buf[b]: 5 rounds x 256 thr x 16 B ----
    auto stage = [&](int b, int g) {
        int plane = g >> 6;            // 64 strips per plane
        int strip = g & 63;
        int ybase = strip * TR;
        const float* pbase = in + (size_t)plane * (H * W);
#pragma unroll
        for (int k = 0; k < STAGE_ROUNDS; ++k) {
            int e   = k * 1024 + tid * 4;      // element in tile
            int lr  = e >> 9;                  // tile row 0..9
            int col = e & (W - 1);
            int gy  = ybase - 1 + lr;
            int gyc = min(max(gy, 0), H - 1);  // clamp; zero-fixed at consume
            const float* src = pbase + (size_t)gyc * W + col;
            // LDS dest: wave-uniform base + lane*16 (linear layout)
            float* dst = &buf[b][k * 1024 + (tid & 192) * 4];
            __builtin_amdgcn_global_load_lds((const unsigned int*)src,
                                             (unsigned int*)dst, 16, 0, 0);
        }
    };

    int rsel = tid >> 7;                 // 0: out rows 0..3, 1: rows 4..7 of tile
    int x0   = (tid & 127) << 2;
    int lr0  = rsel * 4;

    // sorted horizontal triple of one staged row (cols x0-1 .. x0+4)
    auto loadrow = [&](const float* lbuf, int lr, bool zero,
                       float* l, float* m, float* h) {
        const float* rowp = lbuf + lr * W;
        float4 c  = *(const float4*)(rowp + x0);
        float  lf = rowp[(x0 > 0) ? (x0 - 1) : 0];
        float  rg = rowp[(x0 < W - 4) ? (x0 + 4) : (W - 1)];
        if (x0 == 0)     lf = 0.0f;      // true zero-pad at image border
        if (x0 == W - 4) rg = 0.0f;
        if (zero) { c = make_float4(0.f, 0.f, 0.f, 0.f); lf = 0.f; rg = 0.f; }
        float p0 = lf, p1 = c.x, p2 = c.y, p3 = c.z, p4 = c.w, p5 = rg;
        l[0] = f_min3(p0, p1, p2); m[0] = f_med3(p0, p1, p2); h[0] = f_max3(p0, p1, p2);
        l[1] = f_min3(p1, p2, p3); m[1] = f_med3(p1, p2, p3); h[1] = f_max3(p1, p2, p3);
        l[2] = f_min3(p2, p3, p4); m[2] = f_med3(p2, p3, p4); h[2] = f_max3(p2, p3, p4);
        l[3] = f_min3(p3, p4, p5); m[3] = f_med3(p3, p4, p5); h[3] = f_max3(p3, p4, p5);
    };

    // ---- prologue: stage tile 0 ----
    stage(0, bid * TPB);
    __syncthreads();

#pragma unroll 2
    for (int t = 0; t < TPB; ++t) {
        int g     = bid * TPB + t;
        int plane = g >> 6;
        int strip = g & 63;
        int ybase = strip * TR;

        // issue next tile's loads FIRST — they fly during compute below
        if (t + 1 < TPB) stage((t + 1) & 1, g + 1);
        __builtin_amdgcn_sched_barrier(0);   // keep stage-issue above compute

        const float* lbuf = buf[t & 1];
        bool zTop = (strip == 0) && (rsel == 0);            // tile row 0 = gy -1
        bool zBot = (strip == STRIPS - 1) && (rsel == 1);   // tile row 9 = gy H

        float Lw[3][4], Mw[3][4], Hw[3][4];
        loadrow(lbuf, lr0,     zTop,  Lw[0], Mw[0], Hw[0]);
        loadrow(lbuf, lr0 + 1, false, Lw[1], Mw[1], Hw[1]);

        float* obase = out + (size_t)plane * (H * W)
                           + (size_t)(ybase + rsel * 4) * W + x0;
#pragma unroll
        for (int r = 0; r < 4; ++r) {
            bool zl = zBot && (r == 3);      // consuming tile row 9
            loadrow(lbuf, lr0 + r + 2, zl,
                    Lw[(r + 2) % 3], Mw[(r + 2) % 3], Hw[(r + 2) % 3]);
            float res[4];
#pragma unroll
            for (int j = 0; j < 4; ++j) {
                float lo = f_max3(Lw[r % 3][j], Lw[(r + 1) % 3][j], Lw[(r + 2) % 3][j]);
                float mi = f_med3(Mw[r % 3][j], Mw[(r + 1) % 3][j], Mw[(r + 2) % 3][j]);
                float hi = f_min3(Hw[r % 3][j], Hw[(r + 1) % 3][j], Hw[(r + 2) % 3][j]);
                res[j] = f_med3(lo, mi, hi);
            }
            *(float4*)(obase + (size_t)r * W) = make_float4(res[0], res[1], res[2], res[3]);
        }

        // one barrier per tile: (a) all waves done reading buf[t&1] before it
        // is re-staged, (b) vmcnt(0) inside guarantees tile t+1 has landed.
        __syncthreads();
    }
}

extern "C" void kernel_launch(void* const* d_in, const int* in_sizes, int n_in,
                              void* d_out, int out_size, void* d_ws, size_t ws_size,
                              hipStream_t stream) {
    const float* x = (const float*)d_in[0];
    float* out = (float*)d_out;

    // 96 planes x 64 strips = 6144 tiles; 6 tiles/block -> 1024 blocks.
    int planes = out_size / (H * W);              // 96
    int blocks = planes * STRIPS / TPB;           // 1024
    median3x3_kernel<<<dim3(blocks), dim3(256), 0, stream>>>(x, out);
}